// Round 11
// baseline (771.305 us; speedup 1.0000x reference)
//
#include <hip/hip_runtime.h>
#include <math.h>

// Sparse2L round 11: h/out R-part retiled 128x64 -> 128x128 (FM=FN=4): LDS
// frag-read traffic per FLOP -33% (ratio 1.33 -> 2.0 MFMA per ds_read_b128).
// kloop2 (counted vmcnt, reg-fragment cluster, setprio) everywhere in h/out;
// 64KB LDS keeps 2 blocks/CU. xupc unchanged from r10. Bit-identical output.
//  per step: R = x@W - inputs; z = u@V (mini-GEMM in XUPC);
//            x = softthr(x - 2lr*(R@W^T), lr*gamma*up((1+e^-z)/2));  [x bf16]
//            gin = (-e^-z/2) * maxpool2x2(x) * gamma  (fused pool phase);
//            u = softthr(u - lr*(gin@V^T), lr*gamma/10)   [in H kernel]
//  output = x9 @ W

#define NB 4096
#define IN_DIM 512
#define OUT_DIM 4096
#define CAUSES_DIM 256
#define POOLED_DIM 1024

typedef __attribute__((ext_vector_type(8))) short short8;
typedef __attribute__((ext_vector_type(4))) float f32x4;

static constexpr float LR = 0.001f;
static constexpr float GAMMA = 0.1f;

enum { EP_R = 0, EP_OUT, EP_UUP };

__device__ __forceinline__ float softthr(float v, float t) {
    return fmaxf(v - t, 0.0f) + fminf(v + t, 0.0f);
}
__device__ __forceinline__ unsigned short f2bf(float f) {
    unsigned int u = __builtin_bit_cast(unsigned int, f);
    u = (u + 0x7fffu + ((u >> 16) & 1u)) >> 16;
    return (unsigned short)u;
}
__device__ __forceinline__ float bf2f(unsigned short h) {
    return __builtin_bit_cast(float, (unsigned int)h << 16);
}
__device__ __forceinline__ void gload_lds16(const unsigned short* g, unsigned short* l) {
    __builtin_amdgcn_global_load_lds(
        (const __attribute__((address_space(1))) void*)g,
        (__attribute__((address_space(3))) void*)l, 16, 0, 0);
}

// stage ROWS x 64 bf16 tile; linear LDS dest, inverse-swizzled global source.
template<int ROWS, int K>
__device__ __forceinline__ void stage_tile(const unsigned short* __restrict__ g,
                                           unsigned short* l, int row0, int k0, int t)
{
#pragma unroll
    for (int j = 0; j < ROWS / 32; j++) {
        const int idx = j * 256 + t;
        const int row = idx >> 3;
        const int sl  = (idx & 7) ^ (row & 7);
        gload_lds16(g + (size_t)(row0 + row) * K + k0 + sl * 8,
                    l + (size_t)(idx & ~63) * 8);
    }
}

// ---------------------------------------------------------------------------
// 2-buffer counted-vmcnt pipelined K-loop, reg-fragment cluster form (r10):
// {counted vmcnt -> barrier -> ds_read all frags -> lgkmcnt(0) -> barrier ->
//  stage next into freed buffer -> setprio + pure-reg MFMA cluster}.
// ---------------------------------------------------------------------------
template<int BM, int BN, int K>
__device__ __forceinline__ void kloop2(unsigned short* lds,
    const unsigned short* __restrict__ A, const unsigned short* __restrict__ B,
    int m0, int n0, f32x4 (&acc)[BM / 32][BN / 32])
{
    constexpr int FM = BM / 32, FN = BN / 32;
    constexpr int NK = K / 64, ST = (BM + BN) * 64, L = (BM + BN) / 32;
    static_assert(NK >= 2, "pipeline needs >=2 K-tiles");
    const int t = threadIdx.x;
    const int lane = t & 63, wid = t >> 6;
    const int l15 = lane & 15, l7 = lane & 7, g = lane >> 4;
    const int wm0 = (wid >> 1) * (BM / 2), wn0 = (wid & 1) * (BN / 2);

    auto stage = [&](int s, int b) {
        stage_tile<BM, K>(A, lds + b * ST, m0, s * 64, t);
        stage_tile<BN, K>(B, lds + b * ST + BM * 64, n0, s * 64, t);
    };

    short8 af[2][FM], bfv[2][FN];
    auto readfrags = [&](int b) {
        const unsigned short* As = lds + b * ST;
        const unsigned short* Bs = lds + b * ST + BM * 64;
#pragma unroll
        for (int ks = 0; ks < 2; ks++) {
            const int so = (((ks * 4) + g) ^ l7) * 8;
#pragma unroll
            for (int fi = 0; fi < FM; fi++)
                af[ks][fi] = *(const short8*)&As[(wm0 + fi * 16 + l15) * 64 + so];
#pragma unroll
            for (int fj = 0; fj < FN; fj++)
                bfv[ks][fj] = *(const short8*)&Bs[(wn0 + fj * 16 + l15) * 64 + so];
        }
    };
    auto mfma_all = [&]() {
        __builtin_amdgcn_s_setprio(1);
#pragma unroll
        for (int ks = 0; ks < 2; ks++)
#pragma unroll
            for (int fi = 0; fi < FM; fi++)
#pragma unroll
                for (int fj = 0; fj < FN; fj++)
                    acc[fi][fj] = __builtin_amdgcn_mfma_f32_16x16x32_bf16(
                        af[ks][fi], bfv[ks][fj], acc[fi][fj], 0, 0, 0);
        __builtin_amdgcn_s_setprio(0);
    };

    stage(0, 0); stage(1, 1);
    int b = 0;
#pragma unroll 1
    for (int i = 0; i < NK; ++i) {
        if (i < NK - 1)
            asm volatile("s_waitcnt vmcnt(%0)" :: "n"(L) : "memory");
        else
            asm volatile("s_waitcnt vmcnt(0)" ::: "memory");
        __builtin_amdgcn_s_barrier();
        readfrags(b);
        asm volatile("s_waitcnt lgkmcnt(0)" ::: "memory");
        __builtin_amdgcn_sched_barrier(0);
        __builtin_amdgcn_s_barrier();
        if (i + 2 < NK) stage(i + 2, b);
        mfma_all();
        b ^= 1;
    }
}

// ---------------------------------------------------------------------------
// generic GEMM core (EP_R / EP_OUT / EP_UUP); caller provides m0,n0; kloop2
// ---------------------------------------------------------------------------
template<int BM, int BN, int N, int K, int EP>
__device__ void gemm_core(unsigned short* lds, int m0, int n0,
                          const unsigned short* __restrict__ A,
                          const unsigned short* __restrict__ B,
                          const float* __restrict__ auxf,
                          void* __restrict__ out0, void* __restrict__ out1)
{
    constexpr int FM = BM / 32, FN = BN / 32;
    const int t = threadIdx.x, lane = t & 63, wid = t >> 6;
    const int l15 = lane & 15, g = lane >> 4;
    const int wm0 = (wid >> 1) * (BM / 2), wn0 = (wid & 1) * (BN / 2);

    f32x4 acc[FM][FN];
#pragma unroll
    for (int fi = 0; fi < FM; fi++)
#pragma unroll
        for (int fj = 0; fj < FN; fj++) acc[fi][fj] = (f32x4){0.f, 0.f, 0.f, 0.f};

    kloop2<BM, BN, K>(lds, A, B, m0, n0, acc);

#pragma unroll
    for (int fi = 0; fi < FM; fi++) {
#pragma unroll
        for (int fj = 0; fj < FN; fj++) {
#pragma unroll
            for (int r = 0; r < 4; r++) {
                const int row = m0 + wm0 + fi * 16 + g * 4 + r;
                const int col = n0 + wn0 + fj * 16 + l15;
                const float v = acc[fi][fj][r];
                if (EP == EP_R) {
                    ((unsigned short*)out0)[(size_t)row * N + col] =
                        f2bf(v - auxf[(size_t)row * N + col]);
                } else if (EP == EP_OUT) {
                    ((float*)out0)[(size_t)row * N + col] = v;
                } else { // EP_UUP
                    float* up = (float*)out0;
                    const size_t idx = (size_t)row * CAUSES_DIM + col;
                    const float uv = softthr(up[idx] - LR * v, LR * GAMMA * 0.1f);
                    up[idx] = uv;
                    ((unsigned short*)out1)[idx] = f2bf(uv);
                }
            }
        }
    }
}

// ---------------------------------------------------------------------------
// XUPC: x-update GEMM (R@W^T, 128x128) + causes mini-GEMM (u@V) + fused pool.
// LDS: 2x32KB pipeline buffers + 16KB czdc = 80KB -> 2 blocks/CU.
// UNCHANGED from round 10.
// ---------------------------------------------------------------------------
template<bool FIRST, bool POOLF>
__global__ __launch_bounds__(256)
void xupc_kernel(const unsigned short* __restrict__ Rbf,
                 const unsigned short* __restrict__ Wbf,
                 const unsigned short* __restrict__ ubf,
                 const unsigned short* __restrict__ VTbf,
                 unsigned short* __restrict__ xbf,
                 unsigned short* __restrict__ gbf)
{
    constexpr int BM = 128, BN = 128;
    __shared__ unsigned short lds[2 * (BM + BN) * 64 + 8192];  // 80 KB
    unsigned* czdc = (unsigned*)(lds + 2 * (BM + BN) * 64);    // [128][32] cz|dc
    unsigned short* xs = lds;                                  // pool tile 128x130

    const int t = threadIdx.x, lane = t & 63, wid = t >> 6;
    const int l15 = lane & 15, g = lane >> 4;
    const int xcd = blockIdx.x & 7, l = blockIdx.x >> 3;       // l in [0,128)
    const int g2 = l >> 5, r2 = l & 31;
    const int bm = g2 * 8 + (r2 >> 2), bn = xcd * 4 + (r2 & 3);
    const int m0 = bm * BM, n0 = bn * BN;
    const int wm0 = (wid >> 1) * 64, wn0 = (wid & 1) * 64;

    f32x4 acc[4][4];
#pragma unroll
    for (int fi = 0; fi < 4; fi++)
#pragma unroll
        for (int fj = 0; fj < 4; fj++) acc[fi][fj] = (f32x4){0.f, 0.f, 0.f, 0.f};
    kloop2<128, 128, IN_DIM>(lds, Rbf, Wbf, m0, n0, acc);
    __syncthreads();

    // causes mini-GEMM: z[128x32] = u[m0:,:] @ VT rows [bn*32, bn*32+32)
    f32x4 zacc[4][1];
#pragma unroll
    for (int fi = 0; fi < 4; fi++) zacc[fi][0] = (f32x4){0.f, 0.f, 0.f, 0.f};
    kloop2<128, 32, CAUSES_DIM>(lds, ubf, VTbf, m0, bn * 32, zacc);

    {   // z epilogue -> czdc (cz low16 | dc high16), bf16-rounded
        const int zc = (wid & 1) * 16 + l15;
#pragma unroll
        for (int fi = 0; fi < 4; fi++) {
#pragma unroll
            for (int r = 0; r < 4; r++) {
                const int zr = (wid >> 1) * 64 + fi * 16 + g * 4 + r;
                const float e = expf(-zacc[fi][0][r]);
                czdc[zr * 32 + zc] =
                    (unsigned)f2bf(0.5f + 0.5f * e) | ((unsigned)f2bf(-0.5f * e) << 16);
            }
        }
    }
    __syncthreads();

    // x-update epilogue
#pragma unroll
    for (int fi = 0; fi < 4; fi++) {
#pragma unroll
        for (int fj = 0; fj < 4; fj++) {
#pragma unroll
            for (int r = 0; r < 4; r++) {
                const int rloc = wm0 + fi * 16 + g * 4 + r;
                const int cloc = wn0 + fj * 16 + l15;
                const int pl = (cloc & 63) >> 1;
                const float cz = bf2f((unsigned short)(czdc[rloc * 32 + pl] & 0xffffu));
                const size_t idx = (size_t)(m0 + rloc) * OUT_DIM + n0 + cloc;
                const float xold = FIRST ? 0.0f : bf2f(xbf[idx]);
                const float xv = softthr(xold - 2.0f * LR * acc[fi][fj][r],
                                         LR * GAMMA * cz);
                const unsigned short xq = f2bf(xv);
                xbf[idx] = xq;
                if (POOLF) xs[rloc * 130 + cloc] = xq;
            }
        }
    }

    // fused maxpool2x2 + gin
    if (POOLF) {
        __syncthreads();
        const int p = t & 31;              // local pooled col
        const int rbase = (t >> 5) * 16;   // 8 groups x 16 rows
#pragma unroll
        for (int i = 0; i < 16; i++) {
            const int prow = rbase + i;
            const unsigned short* xr = &xs[prow * 130 + 2 * p];
            const float mx = fmaxf(fmaxf(bf2f(xr[0]), bf2f(xr[1])),
                                   fmaxf(bf2f(xr[64]), bf2f(xr[65])));
            const float dcv = bf2f((unsigned short)(czdc[prow * 32 + p] >> 16));
            gbf[(size_t)(m0 + prow) * POOLED_DIM + bn * 32 + p] = f2bf(dcv * mx * GAMMA);
        }
    }
}

// ---------------------------------------------------------------------------
// H: horizontal fusion of R_{t+1} (128 blocks, 128x128) and UUP_t (256 blocks).
// R decode: XCD m-ownership — xcd=bid&7 owns m-blocks [4*xcd,4*xcd+4),
// bn = l&3 (4 n-blocks of 128). Grid = 384 blocks.
// ---------------------------------------------------------------------------
__global__ __launch_bounds__(256)
void h_uup_r_kernel(const unsigned short* __restrict__ gbf,
                    const unsigned short* __restrict__ Vbf,
                    float* __restrict__ u, unsigned short* __restrict__ ubf,
                    const unsigned short* __restrict__ xbf,
                    const unsigned short* __restrict__ WTbf,
                    const float* __restrict__ inputs,
                    unsigned short* __restrict__ Rbf)
{
    __shared__ unsigned short lds[2 * (128 + 128) * 64];   // 64 KB
    if (blockIdx.x < 128) {
        const int bid = blockIdx.x;
        const int xcd = bid & 7, l = bid >> 3;             // l in [0,16)
        const int bm = xcd * 4 + (l >> 2);                 // m-ownership per XCD
        const int bn = l & 3;                              // n-fastest (128-wide)
        gemm_core<128, 128, IN_DIM, OUT_DIM, EP_R>(
            lds, bm * 128, bn * 128, xbf, WTbf, inputs, Rbf, nullptr);
    } else {
        const int bid = blockIdx.x - 128;
        gemm_core<64, 64, CAUSES_DIM, POOLED_DIM, EP_UUP>(
            lds, (bid >> 2) * 64, (bid & 3) * 64, gbf, Vbf, nullptr, u, ubf);
    }
}

__global__ __launch_bounds__(256)
void out_kernel(const unsigned short* __restrict__ xbf,
                const unsigned short* __restrict__ WTbf,
                float* __restrict__ out)
{
    __shared__ unsigned short lds[2 * (128 + 128) * 64];
    const int bid = blockIdx.x;
    const int xcd = bid & 7, l = bid >> 3;
    const int bm = xcd * 4 + (l >> 2);
    const int bn = l & 3;
    gemm_core<128, 128, IN_DIM, OUT_DIM, EP_OUT>(
        lds, bm * 128, bn * 128, xbf, WTbf, nullptr, out, nullptr);
}

// ---------------------------------------------------------------------------
// setup kernels
// ---------------------------------------------------------------------------
// cast + transpose in one pass: direct[r][c]=bf(in[r][c]); transp[c][r]=same
__global__ __launch_bounds__(256)
void prep_k(const float* __restrict__ in, unsigned short* __restrict__ direct,
            unsigned short* __restrict__ transp, int R, int C)
{
    __shared__ float tile[32][33];
    const int bx = blockIdx.x * 32, by = blockIdx.y * 32;
    const int tx = threadIdx.x % 32, ty = threadIdx.x / 32;
#pragma unroll
    for (int i = 0; i < 32; i += 8) {
        const float v = in[(size_t)(by + ty + i) * C + bx + tx];
        tile[ty + i][tx] = v;
        direct[(size_t)(by + ty + i) * C + bx + tx] = f2bf(v);
    }
    __syncthreads();
#pragma unroll
    for (int i = 0; i < 32; i += 8)
        transp[(size_t)(bx + ty + i) * R + by + tx] = f2bf(tile[tx][ty + i]);
}

__global__ void negcast_k(const float* __restrict__ in, unsigned short* __restrict__ out,
                          int n4)
{
    const int i = blockIdx.x * 256 + threadIdx.x;
    if (i >= n4) return;
    float4 v = ((const float4*)in)[i];
    union { unsigned short s[4]; unsigned long long u; } p;
    p.s[0] = f2bf(-v.x); p.s[1] = f2bf(-v.y); p.s[2] = f2bf(-v.z); p.s[3] = f2bf(-v.w);
    ((unsigned long long*)out)[i] = p.u;
}

__global__ void fill_u_k(float* __restrict__ u, unsigned short* __restrict__ ubf, int n) {
    const int i = blockIdx.x * 256 + threadIdx.x;
    if (i >= n) return;
    u[i] = 0.1f;
    ubf[i] = f2bf(0.1f);
}

extern "C" void kernel_launch(void* const* d_in, const int* in_sizes, int n_in,
                              void* d_out, int out_size, void* d_ws, size_t ws_size,
                              hipStream_t stream)
{
    const float* inputs = (const float*)d_in[0];   // [4096, 512]
    const float* W      = (const float*)d_in[1];   // [4096, 512]
    const float* V      = (const float*)d_in[2];   // [256, 1024]
    float* out = (float*)d_out;                    // [4096, 512]

    // workspace (~59 MB)
    char* w = (char*)d_ws;
    unsigned short* xbf  = (unsigned short*)w; w += (size_t)NB * OUT_DIM * 2;
    unsigned short* Rbf  = (unsigned short*)w; w += (size_t)NB * IN_DIM * 2;
    unsigned short* gbf  = (unsigned short*)w; w += (size_t)NB * POOLED_DIM * 2;
    float*          u    = (float*)w;          w += (size_t)NB * CAUSES_DIM * 4;
    unsigned short* ubf  = (unsigned short*)w; w += (size_t)NB * CAUSES_DIM * 2;
    unsigned short* Wbf  = (unsigned short*)w; w += (size_t)OUT_DIM * IN_DIM * 2;
    unsigned short* WTbf = (unsigned short*)w; w += (size_t)OUT_DIM * IN_DIM * 2;
    unsigned short* Vbf  = (unsigned short*)w; w += (size_t)CAUSES_DIM * POOLED_DIM * 2;
    unsigned short* VTbf = (unsigned short*)w;

    // ---- setup (4 launches) ----
    prep_k<<<dim3(IN_DIM / 32, OUT_DIM / 32), 256, 0, stream>>>(W, Wbf, WTbf, OUT_DIM, IN_DIM);
    prep_k<<<dim3(POOLED_DIM / 32, CAUSES_DIM / 32), 256, 0, stream>>>(V, Vbf, VTbf, CAUSES_DIM, POOLED_DIM);
    fill_u_k<<<NB * CAUSES_DIM / 256, 256, 0, stream>>>(u, ubf, NB * CAUSES_DIM);
    negcast_k<<<NB * IN_DIM / 4 / 256, 256, 0, stream>>>(inputs, Rbf, NB * IN_DIM / 4); // R0=-inputs

    // ---- 10-step scan ----
    xupc_kernel<true, true><<<1024, 256, 0, stream>>>(Rbf, Wbf, ubf, VTbf, xbf, gbf); // t=0, x=0
    h_uup_r_kernel<<<384, 256, 0, stream>>>(gbf, Vbf, u, ubf, xbf, WTbf, inputs, Rbf);
    for (int t = 1; t < 8; t++) {
        xupc_kernel<false, true><<<1024, 256, 0, stream>>>(Rbf, Wbf, ubf, VTbf, xbf, gbf);
        h_uup_r_kernel<<<384, 256, 0, stream>>>(gbf, Vbf, u, ubf, xbf, WTbf, inputs, Rbf);
    }
    xupc_kernel<false, false><<<1024, 256, 0, stream>>>(Rbf, Wbf, ubf, VTbf, xbf, gbf); // t=8
    out_kernel<<<128, 256, 0, stream>>>(xbf, WTbf, out);                                 // rec = x9@W
}